// Round 6
// baseline (256.391 us; speedup 1.0000x reference)
//
#include <hip/hip_runtime.h>
#include <hip/hip_cooperative_groups.h>

namespace cg = cooperative_groups;

#define NQ 4096
#define NS 8192
#define DD 256
#define NC 64
#define INFV 1000.0f
#define NBLK 512
#define CONVBLK (NBLK - 1)

typedef __attribute__((ext_vector_type(8))) __bf16 bf16x8;
typedef __attribute__((ext_vector_type(4))) float floatx4;

__device__ inline unsigned short f2bf(float f) {
    unsigned int u = __builtin_bit_cast(unsigned int, f);
    unsigned int r = (u + 0x7FFFu + ((u >> 16) & 1u)) >> 16;
    return (unsigned short)r;
}

__device__ inline bf16x8 cvt8(const float* p) {
    unsigned short tmp[8];
#pragma unroll
    for (int i = 0; i < 8; ++i) tmp[i] = f2bf(p[i]);
    return *(bf16x8*)tmp;
}

// ============ single fused cooperative kernel ============
// Phase A: block 0 = hist/scan/scatter + work-queue build; blocks 1..64 zero
//          mcent/Sc; blocks 1..511 grid-stride bf16 convert + norms + diag.
// grid.sync()
// Phase B: blocks 0..255 accumulate centroids (atomic, 4 blocks/class), then
//          ALL blocks drain the pos-tile work queue (16-query tiles).
// grid.sync()
// Phase C: blocks 0..63 run the centroid-MFMA finalize + reduction.
__global__ __launch_bounds__(256, 2) void k_fused(
    const float* __restrict__ xq, const int* __restrict__ yq,
    const float* __restrict__ xs, const int* __restrict__ ys,
    unsigned short* __restrict__ xqh, unsigned short* __restrict__ xsh,
    float* __restrict__ nq2, float* __restrict__ ns2, float* __restrict__ ldot,
    int* __restrict__ counts, int* __restrict__ qcounts, int* __restrict__ soff,
    int* __restrict__ qoff, int* __restrict__ sperm, int* __restrict__ qperm,
    float* __restrict__ mcent, float* __restrict__ Sc, float* __restrict__ poslog,
    int* __restrict__ qcur, int* __restrict__ nunits, int* __restrict__ workq,
    float* __restrict__ out) {
    cg::grid_group grid = cg::this_grid();

    __shared__ int h4[4][NC], hq4[4][NC], wb4[4][NC], wbq4[4][NC];
    __shared__ float redc[4][256];
    __shared__ float sredc[4];
    __shared__ int qish[16];
    __shared__ float nqsh[16];
    __shared__ float msh[4][16], ssh[4][16];
    __shared__ int ush;
    __shared__ float cntf[64], scs[64], nqs[64], ldts[64], ns2s[64], pls[64], red[64];
    __shared__ int ysh[64];

    const int b = blockIdx.x;
    const int tid = threadIdx.x;
    const int lane = tid & 63;
    const int wave = tid >> 6;
    const int quad = lane >> 4;
    const int l15 = lane & 15;

    // ---------------- Phase A ----------------
    if (b == 0) {
        // hist: 4-wave privatized bins, then scan + scatter + workq build
        ((int*)h4)[tid] = 0;
        ((int*)hq4)[tid] = 0;
        __syncthreads();
        int v[32];
#pragma unroll
        for (int i = 0; i < 16; ++i) {
            int j = tid + i * 256;
            v[i] = ys[j];
            atomicAdd(&h4[wave][v[i]], 1);
            atomicAdd(&hq4[wave][v[i]], 1);
        }
#pragma unroll
        for (int i = 16; i < 32; ++i) {
            int j = tid + i * 256;
            v[i] = ys[j];
            atomicAdd(&h4[wave][v[i]], 1);
        }
        __syncthreads();
        if (tid < NC) {
            const int c = tid;
            int tot = 0, totq = 0;
            int pre[4], preq[4];
#pragma unroll
            for (int w = 0; w < 4; ++w) {
                pre[w] = tot; preq[w] = totq;
                tot += h4[w][c]; totq += hq4[w][c];
            }
            counts[c] = tot; qcounts[c] = totq;
            int ntile = (totq + 15) >> 4;
            int x = tot, xb = totq, tb = ntile;
#pragma unroll
            for (int off = 1; off < 64; off <<= 1) {
                int y0 = __shfl_up(x, off, 64);
                int y1 = __shfl_up(xb, off, 64);
                int y2 = __shfl_up(tb, off, 64);
                if (c >= off) { x += y0; xb += y1; tb += y2; }
            }
            int base = x - tot, baseq = xb - totq, tbase = tb - ntile;
            soff[c] = base; qoff[c] = baseq;
#pragma unroll
            for (int w = 0; w < 4; ++w) {
                wb4[w][c] = base + pre[w];
                wbq4[w][c] = baseq + preq[w];
            }
            for (int t = 0; t < ntile; ++t) workq[tbase + t] = (c << 16) | t;
            if (c == NC - 1) *nunits = tbase + ntile;
            if (c == 0) *qcur = 0;
        }
        __syncthreads();
#pragma unroll
        for (int i = 0; i < 16; ++i) {
            int j = tid + i * 256;
            int c = v[i];
            sperm[atomicAdd(&wb4[wave][c], 1)] = j;
            qperm[atomicAdd(&wbq4[wave][c], 1)] = j;
        }
#pragma unroll
        for (int i = 16; i < 32; ++i) {
            int j = tid + i * 256;
            int c = v[i];
            sperm[atomicAdd(&wb4[wave][c], 1)] = j;
        }
    } else {
        if (b <= NC) {
            // zero centroid accumulators for class b-1
            if (tid < 64)
                ((float4*)(mcent + (size_t)(b - 1) * DD))[tid] =
                    make_float4(0.f, 0.f, 0.f, 0.f);
            if (tid == 64) Sc[b - 1] = 0.0f;
        }
        // streaming convert, grid-stride (one row per wave per step)
        for (int row = (b - 1) * 4 + wave; row < NQ + NS; row += CONVBLK * 4) {
            if (row < NQ) {
                float4 v = ((const float4*)(xq + (size_t)row * DD))[lane];
                float4 bb = ((const float4*)(xs + (size_t)row * DD))[lane];
                float s = v.x * v.x + v.y * v.y + v.z * v.z + v.w * v.w;
                float d = v.x * bb.x + v.y * bb.y + v.z * bb.z + v.w * bb.w;
                ((ushort4*)(xqh + (size_t)row * DD))[lane] =
                    make_ushort4(f2bf(v.x), f2bf(v.y), f2bf(v.z), f2bf(v.w));
#pragma unroll
                for (int off = 32; off; off >>= 1) {
                    s += __shfl_xor(s, off, 64);
                    d += __shfl_xor(d, off, 64);
                }
                if (lane == 0) { nq2[row] = s; ldot[row] = d; }
            } else {
                int r = row - NQ;
                float4 v = ((const float4*)(xs + (size_t)r * DD))[lane];
                float s = v.x * v.x + v.y * v.y + v.z * v.z + v.w * v.w;
                ((ushort4*)(xsh + (size_t)r * DD))[lane] =
                    make_ushort4(f2bf(v.x), f2bf(v.y), f2bf(v.z), f2bf(v.w));
#pragma unroll
                for (int off = 32; off; off >>= 1) s += __shfl_xor(s, off, 64);
                if (lane == 0) ns2[r] = s;
            }
        }
    }
    grid.sync();

    // ---------------- Phase B ----------------
    if (b < 256) {
        // centroid: class c = b>>2, y-slice yb = b&3 (wide atomic form)
        const int c = b >> 2;
        const int yb = b & 3;
        const int mc = counts[c];
        const int sbase = soff[c];
        float4 acc = make_float4(0.f, 0.f, 0.f, 0.f);
        float sacc = 0.0f;
        for (int idx = yb * 4 + wave; idx < mc; idx += 16) {
            int row = sperm[sbase + idx];
            float4 v = ((const float4*)(xs + (size_t)row * DD))[lane];
            acc.x += v.x; acc.y += v.y; acc.z += v.z; acc.w += v.w;
            if (lane == 0) sacc += ns2[row];
        }
        ((float4*)redc[wave])[lane] = acc;
        if (lane == 0) sredc[wave] = sacc;
        __syncthreads();
        if (wave == 0) {
            int k0 = lane * 4;
#pragma unroll
            for (int j = 0; j < 4; ++j) {
                float v = redc[0][k0 + j] + redc[1][k0 + j] + redc[2][k0 + j] +
                          redc[3][k0 + j];
                atomicAdd(&mcent[(size_t)c * DD + k0 + j], v);
            }
            if (lane == 0) atomicAdd(&Sc[c], sredc[0] + sredc[1] + sredc[2] + sredc[3]);
        }
    }

    // pos-tile work queue: all 512 blocks drain it
    const int NU = *nunits;
    while (true) {
        __syncthreads();  // protect qish/msh/ush reuse across units
        if (tid == 0) ush = atomicAdd(qcur, 1);
        __syncthreads();
        int u = ush;
        if (u >= NU) break;
        const int c = workq[u] >> 16;
        const int t = workq[u] & 0xffff;
        const int qc = qcounts[c];
        const int mc = counts[c];
        const int sbase = soff[c];
        const int qbase = qoff[c];
        const float ov = (mc > 1) ? -INFV : 0.0f;
        const int q0 = t * 16;

        if (tid < 16) {
            int idx = q0 + tid;
            int qi = (idx < qc) ? qperm[qbase + idx] : -1;
            qish[tid] = qi;
            nqsh[tid] = (qi >= 0) ? nq2[qi] : 0.0f;
        }
        __syncthreads();

        int qrow = qish[l15];
        int qrowL = qrow < 0 ? 0 : qrow;
        const unsigned short* ap = xqh + (size_t)qrowL * DD + quad * 8;
        bf16x8 afr[8];
#pragma unroll
        for (int ks = 0; ks < 8; ++ks) afr[ks] = *(const bf16x8*)(ap + ks * 32);

        int qid[4];
        float nqr[4];
#pragma unroll
        for (int r = 0; r < 4; ++r) {
            qid[r] = qish[quad * 4 + r];
            nqr[r] = nqsh[quad * 4 + r];
        }

        float mrun[4], srun[4];
#pragma unroll
        for (int r = 0; r < 4; ++r) { mrun[r] = -1e30f; srun[r] = 0.0f; }

        for (int jt = wave * 16; jt < mc; jt += 64) {
            int jcol = jt + l15;
            bool valid = jcol < mc;
            int sj = valid ? sperm[sbase + jcol] : -1;
            int sjL = sj < 0 ? 0 : sj;
            float nsv = valid ? ns2[sjL] : 0.0f;
            const unsigned short* bp = xsh + (size_t)sjL * DD + quad * 8;
            floatx4 acc = (floatx4)0.0f;
#pragma unroll
            for (int ks = 0; ks < 8; ++ks) {
                bf16x8 bfr = *(const bf16x8*)(bp + ks * 32);
                acc = __builtin_amdgcn_mfma_f32_16x16x32_bf16(afr[ks], bfr, acc, 0, 0, 0);
            }
            if (valid) {
#pragma unroll
                for (int r = 0; r < 4; ++r) {
                    float v = fminf(acc[r] - 0.5f * (nqr[r] + nsv), 0.0f);
                    if (sj == qid[r]) v = ov;
                    float mn = fmaxf(mrun[r], v);
                    srun[r] = srun[r] * __expf(mrun[r] - mn) + __expf(v - mn);
                    mrun[r] = mn;
                }
            }
        }
#pragma unroll
        for (int r = 0; r < 4; ++r) {
#pragma unroll
            for (int off = 1; off < 16; off <<= 1) {
                float m2 = __shfl_xor(mrun[r], off, 64);
                float s2 = __shfl_xor(srun[r], off, 64);
                float mn = fmaxf(mrun[r], m2);
                srun[r] = srun[r] * __expf(mrun[r] - mn) + s2 * __expf(m2 - mn);
                mrun[r] = mn;
            }
            if (l15 == 0) {
                msh[wave][quad * 4 + r] = mrun[r];
                ssh[wave][quad * 4 + r] = srun[r];
            }
        }
        __syncthreads();
        if (tid < 16) {
            int qi = qish[tid];
            if (qi >= 0) {
                float m = -1e30f, s = 0.0f;
#pragma unroll
                for (int w = 0; w < 4; ++w) {
                    float mw = msh[w][tid], sw = ssh[w][tid];
                    float mn = fmaxf(m, mw);
                    s = s * __expf(m - mn) + sw * __expf(mw - mn);
                    m = mn;
                }
                poslog[qi] = m + __logf(s);
            }
        }
    }
    grid.sync();

    // ---------------- Phase C: finalize ----------------
    if (b < 64) {
        if (tid < 64) {
            cntf[tid] = (float)counts[tid];
            scs[tid] = Sc[tid];
            int row = b * 64 + tid;
            nqs[tid] = nq2[row];
            ysh[tid] = yq[row];
            ldts[tid] = ldot[row];
            ns2s[tid] = ns2[row];
            pls[tid] = poslog[row];
        }
        __syncthreads();

        const unsigned short* ap =
            xqh + (size_t)(b * 64 + wave * 16 + l15) * DD + quad * 8;
        bf16x8 afr[8];
#pragma unroll
        for (int ks = 0; ks < 8; ++ks) afr[ks] = *(const bf16x8*)(ap + ks * 32);

        floatx4 acc[4];
#pragma unroll
        for (int n = 0; n < 4; ++n) acc[n] = (floatx4)0.0f;

#pragma unroll
        for (int n = 0; n < 4; ++n) {
            const float* bp = mcent + (size_t)(n * 16 + l15) * DD + quad * 8;
#pragma unroll
            for (int ks = 0; ks < 8; ++ks) {
                bf16x8 bfr = cvt8(bp + ks * 32);
                acc[n] =
                    __builtin_amdgcn_mfma_f32_16x16x32_bf16(afr[ks], bfr, acc[n], 0, 0, 0);
            }
        }

#pragma unroll
        for (int r = 0; r < 4; ++r) {
            int rl = wave * 16 + quad * 4 + r;
            float nqv = nqs[rl];
            int y = ysh[rl];
            float vv[4];
#pragma unroll
            for (int n = 0; n < 4; ++n) {
                int col = n * 16 + l15;
                float cnt = cntf[col];
                float val = acc[n][r] - 0.5f * cnt * nqv - 0.5f * scs[col];
                float sub = (col == y) ? 1.0f : 0.0f;
                if (col == y) {
                    float lii = ldts[rl] - 0.5f * (nqv + ns2s[rl]);
                    val += ((cnt > 1.5f) ? -INFV : 0.0f) - lii;
                }
                vv[n] = val / (cnt - sub);
            }
            float m = fmaxf(fmaxf(vv[0], vv[1]), fmaxf(vv[2], vv[3]));
#pragma unroll
            for (int off = 1; off < 16; off <<= 1) m = fmaxf(m, __shfl_xor(m, off, 64));
            float e = __expf(vv[0] - m) + __expf(vv[1] - m) + __expf(vv[2] - m) +
                      __expf(vv[3] - m);
#pragma unroll
            for (int off = 1; off < 16; off <<= 1) e += __shfl_xor(e, off, 64);
            if (l15 == 0) red[rl] = (m + __logf(e) - pls[rl]) * (1.0f / (float)NQ);
        }
        __syncthreads();
        if (tid < 64) {
            float s = red[tid];
#pragma unroll
            for (int off = 32; off; off >>= 1) s += __shfl_xor(s, off, 64);
            if (tid == 0) atomicAdd(out, s);
        }
    }
}

extern "C" void kernel_launch(void* const* d_in, const int* in_sizes, int n_in,
                              void* d_out, int out_size, void* d_ws, size_t ws_size,
                              hipStream_t stream) {
    const float* xq = (const float*)d_in[0];
    const int* yq = (const int*)d_in[1];
    const float* xs = (const float*)d_in[2];
    const int* ys = (const int*)d_in[3];
    float* out = (float*)d_out;
    char* ws = (char*)d_ws;

    unsigned short* xqh = (unsigned short*)(ws + 0);        // 2 MB
    unsigned short* xsh = (unsigned short*)(ws + 2097152);  // 4 MB -> ends 6291456
    float* nq2 = (float*)(ws + 6291456);     // 16 KB
    float* ns2 = (float*)(ws + 6307840);     // 32 KB
    int* counts = (int*)(ws + 6340608);      // 256 B
    int* qcounts = (int*)(ws + 6340864);
    int* soff = (int*)(ws + 6341120);
    int* qoff = (int*)(ws + 6341376);
    int* sperm = (int*)(ws + 6341632);       // 32 KB
    int* qperm = (int*)(ws + 6374400);       // 16 KB
    float* poslog = (float*)(ws + 6390784);  // 16 KB
    float* ldot = (float*)(ws + 6407168);    // 16 KB
    float* mcent = (float*)(ws + 6423552);   // 64 KB fp32, c-major [c*256+k]
    float* Sc = (float*)(ws + 6489088);      // 256 B
    int* qcur = (int*)(ws + 6489344);        // 4 B
    int* nunits = (int*)(ws + 6489348);      // 4 B
    int* workq = (int*)(ws + 6489600);       // 2 KB

    hipMemsetAsync(d_out, 0, (size_t)out_size * 4, stream);

    void* kargs[] = {&xq,     &yq,   &xs,     &ys,   &xqh,    &xsh,  &nq2,
                     &ns2,    &ldot, &counts, &qcounts, &soff, &qoff, &sperm,
                     &qperm,  &mcent, &Sc,    &poslog, &qcur, &nunits, &workq,
                     &out};
    hipLaunchCooperativeKernel((const void*)k_fused, dim3(NBLK), dim3(256), kargs, 0,
                               stream);
}

// Round 8
// 230.931 us; speedup vs baseline: 1.1102x; 1.1102x over previous
//
#include <hip/hip_runtime.h>
#include <hip/hip_cooperative_groups.h>

namespace cg = cooperative_groups;

#define NQ 4096
#define NS 8192
#define DD 256
#define NC 64
#define INFV 1000.0f
#define NBLK 512

typedef __attribute__((ext_vector_type(8))) __bf16 bf16x8;
typedef __attribute__((ext_vector_type(4))) float floatx4;

__device__ inline unsigned short f2bf(float f) {
    unsigned int u = __builtin_bit_cast(unsigned int, f);
    unsigned int r = (u + 0x7FFFu + ((u >> 16) & 1u)) >> 16;
    return (unsigned short)r;
}

__device__ inline bf16x8 cvt8(const float* p) {
    unsigned short tmp[8];
#pragma unroll
    for (int i = 0; i < 8; ++i) tmp[i] = f2bf(p[i]);
    return *(bf16x8*)tmp;
}

// ============ single fused cooperative kernel (static pos-unit map) ============
// Phase A: block 0 = hist/scan/scatter + unit-map build; blocks 1..64 zero
//          mcent/Sc; block 65 zeroes out; blocks 1..511 grid-stride convert.
// grid.sync()
// Phase B: blocks 0..255 accumulate centroids (4 blocks/class); pos units are
//          STATICALLY assigned (no atomics): block 256+u handles unit u<256,
//          block u-256 handles units 256..319 after its centroid slice.
// grid.sync()
// Phase C: blocks 0..63 run the centroid-MFMA finalize + reduction.
__global__ __launch_bounds__(256, 2) void k_fused(
    const float* __restrict__ xq, const int* __restrict__ yq,
    const float* __restrict__ xs, const int* __restrict__ ys,
    unsigned short* __restrict__ xqh, unsigned short* __restrict__ xsh,
    float* __restrict__ nq2, float* __restrict__ ns2, float* __restrict__ ldot,
    int* __restrict__ counts, int* __restrict__ qcounts, int* __restrict__ soff,
    int* __restrict__ qoff, int* __restrict__ sperm, int* __restrict__ qperm,
    float* __restrict__ mcent, float* __restrict__ Sc, float* __restrict__ poslog,
    int* __restrict__ nunits, int* __restrict__ workq, float* __restrict__ out,
    int osz) {
    cg::grid_group grid = cg::this_grid();

    __shared__ int h4[4][NC], hq4[4][NC], wb4[4][NC], wbq4[4][NC];
    __shared__ float redc[4][256];
    __shared__ float sredc[4];
    __shared__ int qish[16];
    __shared__ float nqsh[16];
    __shared__ float msh[4][16], ssh[4][16];
    __shared__ float cntf[64], scs[64], nqs[64], ldts[64], ns2s[64], pls[64], red[64];
    __shared__ int ysh[64];

    const int b = blockIdx.x;
    const int tid = threadIdx.x;
    const int lane = tid & 63;
    const int wave = tid >> 6;
    const int quad = lane >> 4;
    const int l15 = lane & 15;

    // ---------------- Phase A ----------------
    if (b == 0) {
        // hist: 4-wave privatized bins, then scan + scatter + unit map build
        ((int*)h4)[tid] = 0;
        ((int*)hq4)[tid] = 0;
        __syncthreads();
        int v[32];
#pragma unroll
        for (int i = 0; i < 16; ++i) {
            int j = tid + i * 256;
            v[i] = ys[j];
            atomicAdd(&h4[wave][v[i]], 1);
            atomicAdd(&hq4[wave][v[i]], 1);
        }
#pragma unroll
        for (int i = 16; i < 32; ++i) {
            int j = tid + i * 256;
            v[i] = ys[j];
            atomicAdd(&h4[wave][v[i]], 1);
        }
        __syncthreads();
        if (tid < NC) {
            const int c = tid;
            int tot = 0, totq = 0;
            int pre[4], preq[4];
#pragma unroll
            for (int w = 0; w < 4; ++w) {
                pre[w] = tot; preq[w] = totq;
                tot += h4[w][c]; totq += hq4[w][c];
            }
            counts[c] = tot; qcounts[c] = totq;
            int ntile = (totq + 15) >> 4;
            int x = tot, xb = totq, tb = ntile;
#pragma unroll
            for (int off = 1; off < 64; off <<= 1) {
                int y0 = __shfl_up(x, off, 64);
                int y1 = __shfl_up(xb, off, 64);
                int y2 = __shfl_up(tb, off, 64);
                if (c >= off) { x += y0; xb += y1; tb += y2; }
            }
            int base = x - tot, baseq = xb - totq, tbase = tb - ntile;
            soff[c] = base; qoff[c] = baseq;
#pragma unroll
            for (int w = 0; w < 4; ++w) {
                wb4[w][c] = base + pre[w];
                wbq4[w][c] = baseq + preq[w];
            }
            for (int t = 0; t < ntile; ++t) workq[tbase + t] = (c << 16) | t;
            if (c == NC - 1) *nunits = tbase + ntile;
        }
        __syncthreads();
#pragma unroll
        for (int i = 0; i < 16; ++i) {
            int j = tid + i * 256;
            int c = v[i];
            sperm[atomicAdd(&wb4[wave][c], 1)] = j;
            qperm[atomicAdd(&wbq4[wave][c], 1)] = j;
        }
#pragma unroll
        for (int i = 16; i < 32; ++i) {
            int j = tid + i * 256;
            int c = v[i];
            sperm[atomicAdd(&wb4[wave][c], 1)] = j;
        }
    } else {
        if (b <= NC) {
            // zero centroid accumulators for class b-1
            if (tid < 64)
                ((float4*)(mcent + (size_t)(b - 1) * DD))[tid] =
                    make_float4(0.f, 0.f, 0.f, 0.f);
            if (tid == 64) Sc[b - 1] = 0.0f;
        }
        if (b == 65) {
            for (int i = tid; i < osz; i += 256) out[i] = 0.0f;
        }
        // streaming convert, grid-stride (one row per wave per step)
        for (int row = (b - 1) * 4 + wave; row < NQ + NS; row += (NBLK - 1) * 4) {
            if (row < NQ) {
                float4 v = ((const float4*)(xq + (size_t)row * DD))[lane];
                float4 bb = ((const float4*)(xs + (size_t)row * DD))[lane];
                float s = v.x * v.x + v.y * v.y + v.z * v.z + v.w * v.w;
                float d = v.x * bb.x + v.y * bb.y + v.z * bb.z + v.w * bb.w;
                ((ushort4*)(xqh + (size_t)row * DD))[lane] =
                    make_ushort4(f2bf(v.x), f2bf(v.y), f2bf(v.z), f2bf(v.w));
#pragma unroll
                for (int off = 32; off; off >>= 1) {
                    s += __shfl_xor(s, off, 64);
                    d += __shfl_xor(d, off, 64);
                }
                if (lane == 0) { nq2[row] = s; ldot[row] = d; }
            } else {
                int r = row - NQ;
                float4 v = ((const float4*)(xs + (size_t)r * DD))[lane];
                float s = v.x * v.x + v.y * v.y + v.z * v.z + v.w * v.w;
                ((ushort4*)(xsh + (size_t)r * DD))[lane] =
                    make_ushort4(f2bf(v.x), f2bf(v.y), f2bf(v.z), f2bf(v.w));
#pragma unroll
                for (int off = 32; off; off >>= 1) s += __shfl_xor(s, off, 64);
                if (lane == 0) ns2[r] = s;
            }
        }
    }
    grid.sync();

    // ---------------- Phase B ----------------
    if (b < 256) {
        // centroid: class c = b>>2, y-slice yb = b&3 (wide atomic form)
        const int c = b >> 2;
        const int yb = b & 3;
        const int mc = counts[c];
        const int sbase = soff[c];
        float4 acc = make_float4(0.f, 0.f, 0.f, 0.f);
        float sacc = 0.0f;
        for (int idx = yb * 4 + wave; idx < mc; idx += 16) {
            int row = sperm[sbase + idx];
            float4 v = ((const float4*)(xs + (size_t)row * DD))[lane];
            acc.x += v.x; acc.y += v.y; acc.z += v.z; acc.w += v.w;
            if (lane == 0) sacc += ns2[row];
        }
        ((float4*)redc[wave])[lane] = acc;
        if (lane == 0) sredc[wave] = sacc;
        __syncthreads();
        if (wave == 0) {
            int k0 = lane * 4;
#pragma unroll
            for (int j = 0; j < 4; ++j) {
                float v = redc[0][k0 + j] + redc[1][k0 + j] + redc[2][k0 + j] +
                          redc[3][k0 + j];
                atomicAdd(&mcent[(size_t)c * DD + k0 + j], v);
            }
            if (lane == 0) atomicAdd(&Sc[c], sredc[0] + sredc[1] + sredc[2] + sredc[3]);
        }
    }

    // pos units: STATIC assignment, no queue atomics.
    // blocks 256..511 -> units 0..255 (start immediately);
    // blocks 0..63    -> units 256..NU-1 (after centroid slice). NU <= 320.
    const int NU = *nunits;
    const int u = (b >= 256) ? (b - 256) : (256 + b);
    if (u < NU) {
        const int c = workq[u] >> 16;
        const int t = workq[u] & 0xffff;
        const int qc = qcounts[c];
        const int mc = counts[c];
        const int sbase = soff[c];
        const int qbase = qoff[c];
        const float ov = (mc > 1) ? -INFV : 0.0f;
        const int q0 = t * 16;

        if (tid < 16) {
            int idx = q0 + tid;
            int qi = (idx < qc) ? qperm[qbase + idx] : -1;
            qish[tid] = qi;
            nqsh[tid] = (qi >= 0) ? nq2[qi] : 0.0f;
        }
        __syncthreads();

        int qrow = qish[l15];
        int qrowL = qrow < 0 ? 0 : qrow;
        const unsigned short* ap = xqh + (size_t)qrowL * DD + quad * 8;
        bf16x8 afr[8];
#pragma unroll
        for (int ks = 0; ks < 8; ++ks) afr[ks] = *(const bf16x8*)(ap + ks * 32);

        int qid[4];
        float nqr[4];
#pragma unroll
        for (int r = 0; r < 4; ++r) {
            qid[r] = qish[quad * 4 + r];
            nqr[r] = nqsh[quad * 4 + r];
        }

        float mrun[4], srun[4];
#pragma unroll
        for (int r = 0; r < 4; ++r) { mrun[r] = -1e30f; srun[r] = 0.0f; }

        for (int jt = wave * 16; jt < mc; jt += 64) {
            int jcol = jt + l15;
            bool valid = jcol < mc;
            int sj = valid ? sperm[sbase + jcol] : -1;
            int sjL = sj < 0 ? 0 : sj;
            float nsv = valid ? ns2[sjL] : 0.0f;
            const unsigned short* bp = xsh + (size_t)sjL * DD + quad * 8;
            floatx4 acc = (floatx4)0.0f;
#pragma unroll
            for (int ks = 0; ks < 8; ++ks) {
                bf16x8 bfr = *(const bf16x8*)(bp + ks * 32);
                acc = __builtin_amdgcn_mfma_f32_16x16x32_bf16(afr[ks], bfr, acc, 0, 0, 0);
            }
            if (valid) {
#pragma unroll
                for (int r = 0; r < 4; ++r) {
                    float v = fminf(acc[r] - 0.5f * (nqr[r] + nsv), 0.0f);
                    if (sj == qid[r]) v = ov;
                    float mn = fmaxf(mrun[r], v);
                    srun[r] = srun[r] * __expf(mrun[r] - mn) + __expf(v - mn);
                    mrun[r] = mn;
                }
            }
        }
#pragma unroll
        for (int r = 0; r < 4; ++r) {
#pragma unroll
            for (int off = 1; off < 16; off <<= 1) {
                float m2 = __shfl_xor(mrun[r], off, 64);
                float s2 = __shfl_xor(srun[r], off, 64);
                float mn = fmaxf(mrun[r], m2);
                srun[r] = srun[r] * __expf(mrun[r] - mn) + s2 * __expf(m2 - mn);
                mrun[r] = mn;
            }
            if (l15 == 0) {
                msh[wave][quad * 4 + r] = mrun[r];
                ssh[wave][quad * 4 + r] = srun[r];
            }
        }
        __syncthreads();
        if (tid < 16) {
            int qi = qish[tid];
            if (qi >= 0) {
                float m = -1e30f, s = 0.0f;
#pragma unroll
                for (int w = 0; w < 4; ++w) {
                    float mw = msh[w][tid], sw = ssh[w][tid];
                    float mn = fmaxf(m, mw);
                    s = s * __expf(m - mn) + sw * __expf(mw - mn);
                    m = mn;
                }
                poslog[qi] = m + __logf(s);
            }
        }
    }
    grid.sync();

    // ---------------- Phase C: finalize ----------------
    if (b < 64) {
        if (tid < 64) {
            cntf[tid] = (float)counts[tid];
            scs[tid] = Sc[tid];
            int row = b * 64 + tid;
            nqs[tid] = nq2[row];
            ysh[tid] = yq[row];
            ldts[tid] = ldot[row];
            ns2s[tid] = ns2[row];
            pls[tid] = poslog[row];
        }
        __syncthreads();

        const unsigned short* ap =
            xqh + (size_t)(b * 64 + wave * 16 + l15) * DD + quad * 8;
        bf16x8 afr[8];
#pragma unroll
        for (int ks = 0; ks < 8; ++ks) afr[ks] = *(const bf16x8*)(ap + ks * 32);

        floatx4 acc[4];
#pragma unroll
        for (int n = 0; n < 4; ++n) acc[n] = (floatx4)0.0f;

#pragma unroll
        for (int n = 0; n < 4; ++n) {
            const float* bp = mcent + (size_t)(n * 16 + l15) * DD + quad * 8;
#pragma unroll
            for (int ks = 0; ks < 8; ++ks) {
                bf16x8 bfr = cvt8(bp + ks * 32);
                acc[n] =
                    __builtin_amdgcn_mfma_f32_16x16x32_bf16(afr[ks], bfr, acc[n], 0, 0, 0);
            }
        }

#pragma unroll
        for (int r = 0; r < 4; ++r) {
            int rl = wave * 16 + quad * 4 + r;
            float nqv = nqs[rl];
            int y = ysh[rl];
            float vv[4];
#pragma unroll
            for (int n = 0; n < 4; ++n) {
                int col = n * 16 + l15;
                float cnt = cntf[col];
                float val = acc[n][r] - 0.5f * cnt * nqv - 0.5f * scs[col];
                float sub = (col == y) ? 1.0f : 0.0f;
                if (col == y) {
                    float lii = ldts[rl] - 0.5f * (nqv + ns2s[rl]);
                    val += ((cnt > 1.5f) ? -INFV : 0.0f) - lii;
                }
                vv[n] = val / (cnt - sub);
            }
            float m = fmaxf(fmaxf(vv[0], vv[1]), fmaxf(vv[2], vv[3]));
#pragma unroll
            for (int off = 1; off < 16; off <<= 1) m = fmaxf(m, __shfl_xor(m, off, 64));
            float e = __expf(vv[0] - m) + __expf(vv[1] - m) + __expf(vv[2] - m) +
                      __expf(vv[3] - m);
#pragma unroll
            for (int off = 1; off < 16; off <<= 1) e += __shfl_xor(e, off, 64);
            if (l15 == 0) red[rl] = (m + __logf(e) - pls[rl]) * (1.0f / (float)NQ);
        }
        __syncthreads();
        if (tid < 64) {
            float s = red[tid];
#pragma unroll
            for (int off = 32; off; off >>= 1) s += __shfl_xor(s, off, 64);
            if (tid == 0) atomicAdd(out, s);
        }
    }
}

extern "C" void kernel_launch(void* const* d_in, const int* in_sizes, int n_in,
                              void* d_out, int out_size, void* d_ws, size_t ws_size,
                              hipStream_t stream) {
    const float* xq = (const float*)d_in[0];
    const int* yq = (const int*)d_in[1];
    const float* xs = (const float*)d_in[2];
    const int* ys = (const int*)d_in[3];
    float* out = (float*)d_out;
    char* ws = (char*)d_ws;

    unsigned short* xqh = (unsigned short*)(ws + 0);        // 2 MB
    unsigned short* xsh = (unsigned short*)(ws + 2097152);  // 4 MB -> ends 6291456
    float* nq2 = (float*)(ws + 6291456);     // 16 KB
    float* ns2 = (float*)(ws + 6307840);     // 32 KB
    int* counts = (int*)(ws + 6340608);      // 256 B
    int* qcounts = (int*)(ws + 6340864);
    int* soff = (int*)(ws + 6341120);
    int* qoff = (int*)(ws + 6341376);
    int* sperm = (int*)(ws + 6341632);       // 32 KB
    int* qperm = (int*)(ws + 6374400);       // 16 KB
    float* poslog = (float*)(ws + 6390784);  // 16 KB
    float* ldot = (float*)(ws + 6407168);    // 16 KB
    float* mcent = (float*)(ws + 6423552);   // 64 KB fp32, c-major [c*256+k]
    float* Sc = (float*)(ws + 6489088);      // 256 B
    int* nunits = (int*)(ws + 6489348);      // 4 B
    int* workq = (int*)(ws + 6489600);       // 2 KB

    int osz = out_size;

    void* kargs[] = {&xq,   &yq,     &xs,   &ys,     &xqh,  &xsh,    &nq2,
                     &ns2,  &ldot,   &counts, &qcounts, &soff, &qoff, &sperm,
                     &qperm, &mcent, &Sc,   &poslog, &nunits, &workq, &out,
                     &osz};
    hipLaunchCooperativeKernel((const void*)k_fused, dim3(NBLK), dim3(256), kargs, 0,
                               stream);
}

// Round 19
// 107.153 us; speedup vs baseline: 2.3927x; 2.1551x over previous
//
#include <hip/hip_runtime.h>

#define NQ 4096
#define NS 8192
#define DD 256
#define NC 64
#define INFV 1000.0f

typedef __attribute__((ext_vector_type(8))) __bf16 bf16x8;
typedef __attribute__((ext_vector_type(4))) float floatx4;

__device__ inline unsigned short f2bf(float f) {
    unsigned int u = __builtin_bit_cast(unsigned int, f);
    unsigned int r = (u + 0x7FFFu + ((u >> 16) & 1u)) >> 16;
    return (unsigned short)r;
}

__device__ inline bf16x8 cvt8(const float* p) {
    unsigned short tmp[8];
#pragma unroll
    for (int i = 0; i < 8; ++i) tmp[i] = f2bf(p[i]);
    return *(bf16x8*)tmp;
}

// ---------------- K1: hist (block 0) + convert/norms/diag + zero-init ----------------
__global__ __launch_bounds__(256) void k_prep_hist(const float* __restrict__ xq,
                                                   const float* __restrict__ xs,
                                                   const int* __restrict__ ys,
                                                   unsigned short* __restrict__ xqh,
                                                   unsigned short* __restrict__ xsh,
                                                   float* __restrict__ nq2,
                                                   float* __restrict__ ns2,
                                                   float* __restrict__ ldot,
                                                   int* __restrict__ counts,
                                                   int* __restrict__ qcounts,
                                                   int* __restrict__ soff,
                                                   int* __restrict__ qoff,
                                                   int* __restrict__ sperm,
                                                   int* __restrict__ qperm,
                                                   int* __restrict__ nunits,
                                                   int* __restrict__ workq,
                                                   float* __restrict__ mcent,
                                                   float* __restrict__ Sc,
                                                   float* __restrict__ out, int osz) {
    __shared__ int h4[4][NC], hq4[4][NC], wb4[4][NC], wbq4[4][NC];
    const int tid = threadIdx.x;
    const int b = blockIdx.x;

    if (b == 0) {
        // ---- histogram block: 256 threads, 4-wave privatized bins ----
        const int wave = tid >> 6;
        ((int*)h4)[tid] = 0;
        ((int*)hq4)[tid] = 0;
        __syncthreads();
        int v[32];
#pragma unroll
        for (int i = 0; i < 16; ++i) {
            int j = tid + i * 256;
            v[i] = ys[j];
            atomicAdd(&h4[wave][v[i]], 1);
            atomicAdd(&hq4[wave][v[i]], 1);
        }
#pragma unroll
        for (int i = 16; i < 32; ++i) {
            int j = tid + i * 256;
            v[i] = ys[j];
            atomicAdd(&h4[wave][v[i]], 1);
        }
        __syncthreads();
        if (tid < NC) {
            const int c = tid;
            int tot = 0, totq = 0;
            int pre[4], preq[4];
#pragma unroll
            for (int w = 0; w < 4; ++w) {
                pre[w] = tot; preq[w] = totq;
                tot += h4[w][c]; totq += hq4[w][c];
            }
            counts[c] = tot; qcounts[c] = totq;
            int ntile = (totq + 15) >> 4;
            int x = tot, xb = totq, tb = ntile;
#pragma unroll
            for (int off = 1; off < 64; off <<= 1) {
                int y0 = __shfl_up(x, off, 64);
                int y1 = __shfl_up(xb, off, 64);
                int y2 = __shfl_up(tb, off, 64);
                if (c >= off) { x += y0; xb += y1; tb += y2; }
            }
            int base = x - tot, baseq = xb - totq, tbase = tb - ntile;
            soff[c] = base; qoff[c] = baseq;
#pragma unroll
            for (int w = 0; w < 4; ++w) {
                wb4[w][c] = base + pre[w];
                wbq4[w][c] = baseq + preq[w];
            }
            for (int t = 0; t < ntile; ++t) workq[tbase + t] = (c << 16) | t;
            if (c == NC - 1) *nunits = tbase + ntile;
        }
        __syncthreads();
#pragma unroll
        for (int i = 0; i < 16; ++i) {
            int j = tid + i * 256;
            int c = v[i];
            sperm[atomicAdd(&wb4[wave][c], 1)] = j;
            qperm[atomicAdd(&wbq4[wave][c], 1)] = j;
        }
#pragma unroll
        for (int i = 16; i < 32; ++i) {
            int j = tid + i * 256;
            int c = v[i];
            sperm[atomicAdd(&wb4[wave][c], 1)] = j;
        }
        return;
    }

    // zero-init duties folded into the first convert blocks
    if (b <= NC) {
        if (tid < 64)
            ((float4*)(mcent + (size_t)(b - 1) * DD))[tid] = make_float4(0.f, 0.f, 0.f, 0.f);
        if (tid == 64) Sc[b - 1] = 0.0f;
    }
    if (b == 65) {
        for (int i = tid; i < osz; i += 256) out[i] = 0.0f;
    }

    // ---- streaming convert blocks (4 rows per block) ----
    int row = (b - 1) * 4 + (tid >> 6);
    int lane = tid & 63;
    if (row < NQ) {
        float4 v = ((const float4*)(xq + (size_t)row * DD))[lane];
        float4 bb = ((const float4*)(xs + (size_t)row * DD))[lane];
        float s = v.x * v.x + v.y * v.y + v.z * v.z + v.w * v.w;
        float d = v.x * bb.x + v.y * bb.y + v.z * bb.z + v.w * bb.w;
        ((ushort4*)(xqh + (size_t)row * DD))[lane] =
            make_ushort4(f2bf(v.x), f2bf(v.y), f2bf(v.z), f2bf(v.w));
#pragma unroll
        for (int off = 32; off; off >>= 1) {
            s += __shfl_xor(s, off, 64);
            d += __shfl_xor(d, off, 64);
        }
        if (lane == 0) { nq2[row] = s; ldot[row] = d; }
    } else {
        int r = row - NQ;
        float4 v = ((const float4*)(xs + (size_t)r * DD))[lane];
        float s = v.x * v.x + v.y * v.y + v.z * v.z + v.w * v.w;
        ((ushort4*)(xsh + (size_t)r * DD))[lane] =
            make_ushort4(f2bf(v.x), f2bf(v.y), f2bf(v.z), f2bf(v.w));
#pragma unroll
        for (int off = 32; off; off >>= 1) s += __shfl_xor(s, off, 64);
        if (lane == 0) ns2[r] = s;
    }
}

// ---------------- K2: wide centroid (blocks 0..255) + static pos units (256..575) ----
__global__ __launch_bounds__(256) void k_cent_pos(const float* __restrict__ xs,
                                                  const unsigned short* __restrict__ xqh,
                                                  const unsigned short* __restrict__ xsh,
                                                  const float* __restrict__ nq2,
                                                  const float* __restrict__ ns2,
                                                  const int* __restrict__ counts,
                                                  const int* __restrict__ qcounts,
                                                  const int* __restrict__ soff,
                                                  const int* __restrict__ qoff,
                                                  const int* __restrict__ sperm,
                                                  const int* __restrict__ qperm,
                                                  const int* __restrict__ nunits,
                                                  const int* __restrict__ workq,
                                                  float* __restrict__ mcent,
                                                  float* __restrict__ Sc,
                                                  float* __restrict__ poslog) {
    __shared__ float redc[4][256];
    __shared__ float sredc[4];
    __shared__ int qish[16];
    __shared__ float nqsh[16];
    __shared__ float msh[4][16], ssh[4][16];

    const int b = blockIdx.x;
    const int tid = threadIdx.x;
    const int lane = tid & 63;
    const int wave = tid >> 6;
    const int quad = lane >> 4;
    const int l15 = lane & 15;

    if (b < 256) {
        // ---- centroid: class c = b>>2, y-slice yb = b&3 ----
        const int c = b >> 2;
        const int yb = b & 3;
        const int mc = counts[c];
        const int sbase = soff[c];
        float4 acc = make_float4(0.f, 0.f, 0.f, 0.f);
        float sacc = 0.0f;
        for (int idx = yb * 4 + wave; idx < mc; idx += 16) {
            int row = sperm[sbase + idx];
            float4 v = ((const float4*)(xs + (size_t)row * DD))[lane];
            acc.x += v.x; acc.y += v.y; acc.z += v.z; acc.w += v.w;
            if (lane == 0) sacc += ns2[row];
        }
        ((float4*)redc[wave])[lane] = acc;
        if (lane == 0) sredc[wave] = sacc;
        __syncthreads();
        if (wave == 0) {
            int k0 = lane * 4;
#pragma unroll
            for (int j = 0; j < 4; ++j) {
                float v = redc[0][k0 + j] + redc[1][k0 + j] + redc[2][k0 + j] +
                          redc[3][k0 + j];
                atomicAdd(&mcent[(size_t)c * DD + k0 + j], v);
            }
            if (lane == 0) atomicAdd(&Sc[c], sredc[0] + sredc[1] + sredc[2] + sredc[3]);
        }
        return;
    }

    // ---- pos unit u = b - 256 (static, no atomics) ----
    const int NU = *nunits;
    const int u = b - 256;
    if (u >= NU) return;
    const int c = workq[u] >> 16;
    const int t = workq[u] & 0xffff;
    const int qc = qcounts[c];
    const int mc = counts[c];
    const int sbase = soff[c];
    const int qbase = qoff[c];
    const float ov = (mc > 1) ? -INFV : 0.0f;
    const int q0 = t * 16;

    if (tid < 16) {
        int idx = q0 + tid;
        int qi = (idx < qc) ? qperm[qbase + idx] : -1;
        qish[tid] = qi;
        nqsh[tid] = (qi >= 0) ? nq2[qi] : 0.0f;
    }
    __syncthreads();

    int qrow = qish[l15];
    int qrowL = qrow < 0 ? 0 : qrow;
    const unsigned short* ap = xqh + (size_t)qrowL * DD + quad * 8;
    bf16x8 afr[8];
#pragma unroll
    for (int ks = 0; ks < 8; ++ks) afr[ks] = *(const bf16x8*)(ap + ks * 32);

    int qid[4];
    float nqr[4];
#pragma unroll
    for (int r = 0; r < 4; ++r) {
        qid[r] = qish[quad * 4 + r];
        nqr[r] = nqsh[quad * 4 + r];
    }

    float mrun[4], srun[4];
#pragma unroll
    for (int r = 0; r < 4; ++r) { mrun[r] = -1e30f; srun[r] = 0.0f; }

    for (int jt = wave * 16; jt < mc; jt += 64) {
        int jcol = jt + l15;
        bool valid = jcol < mc;
        int sj = valid ? sperm[sbase + jcol] : -1;
        int sjL = sj < 0 ? 0 : sj;
        float nsv = valid ? ns2[sjL] : 0.0f;
        const unsigned short* bp = xsh + (size_t)sjL * DD + quad * 8;
        floatx4 acc = (floatx4)0.0f;
#pragma unroll
        for (int ks = 0; ks < 8; ++ks) {
            bf16x8 bfr = *(const bf16x8*)(bp + ks * 32);
            acc = __builtin_amdgcn_mfma_f32_16x16x32_bf16(afr[ks], bfr, acc, 0, 0, 0);
        }
        if (valid) {
#pragma unroll
            for (int r = 0; r < 4; ++r) {
                float v = fminf(acc[r] - 0.5f * (nqr[r] + nsv), 0.0f);
                if (sj == qid[r]) v = ov;
                float mn = fmaxf(mrun[r], v);
                srun[r] = srun[r] * __expf(mrun[r] - mn) + __expf(v - mn);
                mrun[r] = mn;
            }
        }
    }
#pragma unroll
    for (int r = 0; r < 4; ++r) {
#pragma unroll
        for (int off = 1; off < 16; off <<= 1) {
            float m2 = __shfl_xor(mrun[r], off, 64);
            float s2 = __shfl_xor(srun[r], off, 64);
            float mn = fmaxf(mrun[r], m2);
            srun[r] = srun[r] * __expf(mrun[r] - mn) + s2 * __expf(m2 - mn);
            mrun[r] = mn;
        }
        if (l15 == 0) {
            msh[wave][quad * 4 + r] = mrun[r];
            ssh[wave][quad * 4 + r] = srun[r];
        }
    }
    __syncthreads();
    if (tid < 16) {
        int qi = qish[tid];
        if (qi >= 0) {
            float m = -1e30f, s = 0.0f;
#pragma unroll
            for (int w = 0; w < 4; ++w) {
                float mw = msh[w][tid], sw = ssh[w][tid];
                float mn = fmaxf(m, mw);
                s = s * __expf(m - mn) + sw * __expf(mw - mn);
                m = mn;
            }
            poslog[qi] = m + __logf(s);
        }
    }
}

// ---------------- K3: summed via centroid MFMA + finalize ----------------
__global__ __launch_bounds__(256) void k_final(const unsigned short* __restrict__ xqh,
                                               const float* __restrict__ mcent,
                                               const float* __restrict__ Sc,
                                               const int* __restrict__ counts,
                                               const int* __restrict__ yq,
                                               const float* __restrict__ nq2,
                                               const float* __restrict__ ns2,
                                               const float* __restrict__ ldot,
                                               const float* __restrict__ poslog,
                                               float* __restrict__ out) {
    __shared__ float cntf[64], scs[64], nqs[64], ldts[64], ns2s[64], pls[64], red[64];
    __shared__ int ysh[64];

    const int b = blockIdx.x;
    const int tid = threadIdx.x;
    const int lane = tid & 63;
    const int wave = tid >> 6;
    const int quad = lane >> 4;
    const int l15 = lane & 15;

    if (tid < 64) {
        cntf[tid] = (float)counts[tid];
        scs[tid] = Sc[tid];
        int row = b * 64 + tid;
        nqs[tid] = nq2[row];
        ysh[tid] = yq[row];
        ldts[tid] = ldot[row];
        ns2s[tid] = ns2[row];
        pls[tid] = poslog[row];
    }
    __syncthreads();

    const unsigned short* ap = xqh + (size_t)(b * 64 + wave * 16 + l15) * DD + quad * 8;
    bf16x8 afr[8];
#pragma unroll
    for (int ks = 0; ks < 8; ++ks) afr[ks] = *(const bf16x8*)(ap + ks * 32);

    floatx4 acc[4];
#pragma unroll
    for (int n = 0; n < 4; ++n) acc[n] = (floatx4)0.0f;

#pragma unroll
    for (int n = 0; n < 4; ++n) {
        const float* bp = mcent + (size_t)(n * 16 + l15) * DD + quad * 8;
#pragma unroll
        for (int ks = 0; ks < 8; ++ks) {
            bf16x8 bfr = cvt8(bp + ks * 32);
            acc[n] = __builtin_amdgcn_mfma_f32_16x16x32_bf16(afr[ks], bfr, acc[n], 0, 0, 0);
        }
    }

#pragma unroll
    for (int r = 0; r < 4; ++r) {
        int rl = wave * 16 + quad * 4 + r;
        float nqv = nqs[rl];
        int y = ysh[rl];
        float vv[4];
#pragma unroll
        for (int n = 0; n < 4; ++n) {
            int col = n * 16 + l15;
            float cnt = cntf[col];
            float val = acc[n][r] - 0.5f * cnt * nqv - 0.5f * scs[col];
            float sub = (col == y) ? 1.0f : 0.0f;
            if (col == y) {
                float lii = ldts[rl] - 0.5f * (nqv + ns2s[rl]);
                val += ((cnt > 1.5f) ? -INFV : 0.0f) - lii;
            }
            vv[n] = val / (cnt - sub);
        }
        float m = fmaxf(fmaxf(vv[0], vv[1]), fmaxf(vv[2], vv[3]));
#pragma unroll
        for (int off = 1; off < 16; off <<= 1) m = fmaxf(m, __shfl_xor(m, off, 64));
        float e = __expf(vv[0] - m) + __expf(vv[1] - m) + __expf(vv[2] - m) +
                  __expf(vv[3] - m);
#pragma unroll
        for (int off = 1; off < 16; off <<= 1) e += __shfl_xor(e, off, 64);
        if (l15 == 0) red[rl] = (m + __logf(e) - pls[rl]) * (1.0f / (float)NQ);
    }
    __syncthreads();
    if (tid < 64) {
        float s = red[tid];
#pragma unroll
        for (int off = 32; off; off >>= 1) s += __shfl_xor(s, off, 64);
        if (tid == 0) atomicAdd(out, s);
    }
}

extern "C" void kernel_launch(void* const* d_in, const int* in_sizes, int n_in,
                              void* d_out, int out_size, void* d_ws, size_t ws_size,
                              hipStream_t stream) {
    const float* xq = (const float*)d_in[0];
    const int* yq = (const int*)d_in[1];
    const float* xs = (const float*)d_in[2];
    const int* ys = (const int*)d_in[3];
    float* out = (float*)d_out;
    char* ws = (char*)d_ws;

    unsigned short* xqh = (unsigned short*)(ws + 0);        // 2 MB
    unsigned short* xsh = (unsigned short*)(ws + 2097152);  // 4 MB -> ends 6291456
    float* nq2 = (float*)(ws + 6291456);     // 16 KB
    float* ns2 = (float*)(ws + 6307840);     // 32 KB
    int* counts = (int*)(ws + 6340608);      // 256 B
    int* qcounts = (int*)(ws + 6340864);
    int* soff = (int*)(ws + 6341120);
    int* qoff = (int*)(ws + 6341376);
    int* sperm = (int*)(ws + 6341632);       // 32 KB
    int* qperm = (int*)(ws + 6374400);       // 16 KB
    float* poslog = (float*)(ws + 6390784);  // 16 KB
    float* ldot = (float*)(ws + 6407168);    // 16 KB
    float* mcent = (float*)(ws + 6423552);   // 64 KB fp32, c-major [c*256+k]
    float* Sc = (float*)(ws + 6489088);      // 256 B
    int* nunits = (int*)(ws + 6489348);      // 4 B
    int* workq = (int*)(ws + 6489600);       // 2 KB

    k_prep_hist<<<dim3((NQ + NS) / 4 + 1), dim3(256), 0, stream>>>(
        xq, xs, ys, xqh, xsh, nq2, ns2, ldot, counts, qcounts, soff, qoff, sperm,
        qperm, nunits, workq, mcent, Sc, out, out_size);
    k_cent_pos<<<dim3(576), dim3(256), 0, stream>>>(xs, xqh, xsh, nq2, ns2, counts,
                                                    qcounts, soff, qoff, sperm, qperm,
                                                    nunits, workq, mcent, Sc, poslog);
    k_final<<<dim3(64), dim3(256), 0, stream>>>(xqh, mcent, Sc, counts, yq, nq2, ns2,
                                                ldot, poslog, out);
}